// Round 7
// baseline (461.873 us; speedup 1.0000x reference)
//
#include <hip/hip_runtime.h>
#include <hip/hip_bf16.h>

#define DEV static __device__ __forceinline__

constexpr int F1 = 128;   // input features
constexpr int H1 = 8;     // heads layer1
constexpr int C  = 64;    // channels per head
constexpr int B  = 64;    // graphs
constexpr int K  = 10;    // classes
constexpr float NEG = 0.2f;
constexpr unsigned SMASK = 0x07FFFFFFu;   // col[] low bits = src id; bits 27-30 = dest&15

typedef __attribute__((ext_vector_type(8))) short short8;
typedef __attribute__((ext_vector_type(4))) float floatx4;

DEV float b2f(__hip_bfloat16 x) { return __bfloat162float(x); }
DEV float elu1(float v) { return v > 0.f ? v : (__expf(v) - 1.f); }
DEV unsigned short f2bbits(float f) {
  __hip_bfloat16 b = __float2bfloat16(f);
  return *(unsigned short*)&b;
}
DEV float blo(unsigned u) { return __uint_as_float(u << 16); }
DEV float bhi(unsigned u) { return __uint_as_float(u & 0xffff0000u); }
DEV float bu(unsigned short u) { return __uint_as_float(((unsigned)u) << 16); }
DEV unsigned pack2(float lo, float hi) {
  return (unsigned)f2bbits(lo) | ((unsigned)f2bbits(hi) << 16);
}
// 1/x via v_rcp_f32 + one Newton step
DEV float rcp_nr(float x) {
  float r = __builtin_amdgcn_rcpf(x);
  return r * (2.f - x * r);
}

// out1 PERMUTED layout: position p = hp*128 + l16*8 + nt  <->  natural channel
// c = hp*128 + nt*16 + l16. W2frag k-rows and b1 permuted to match.
// W1frag k is NATURAL.

// Self-detection: thread 0 samples 128 even-index bf16 reinterps of x.
DEV int detect_dev(const void* xraw, int* lds) {
  if (threadIdx.x == 0) {
    const __hip_bfloat16* xb = (const __hip_bfloat16*)xraw;
    int bad = 0;
    for (int i = 0; i < 128; ++i) {
      float v = b2f(xb[2 * i]);
      if (!(fabsf(v) < 1e4f)) bad++;
    }
    *lds = (bad < 13) ? 1 : 0;     // 1 = bf16, 0 = f32
  }
  __syncthreads();
  return *lds;
}

#define CVT(p, i) (isbf ? b2f(((const __hip_bfloat16*)(p))[i]) : ((const float*)(p))[i])

// ---------- fused prep ----------
__global__ void fused_prep_kernel(const void* x_raw, const void* w1raw,
                                  const void* as1r, const void* ad1r, const void* b1r,
                                  const void* w2raw,
                                  const void* as2r, const void* ad2r, const void* b2r,
                                  const void* l1wr, const void* l1br,
                                  const void* l2wr, const void* l2br,
                                  unsigned short* __restrict__ xbf,
                                  unsigned short* __restrict__ w1frag,
                                  unsigned short* __restrict__ w2frag,
                                  unsigned short* __restrict__ vfrag,
                                  float* __restrict__ wts,
                                  int* __restrict__ deg,
                                  float* __restrict__ pooled,
                                  float* __restrict__ dng,
                                  int nX, int N) {
  __shared__ int fl;
  int isbf = detect_dev(x_raw, &fl);
  int gid = blockIdx.x * 256 + threadIdx.x;
  int stride = gridDim.x * 256;

  if (isbf) {
    const unsigned short* src = (const unsigned short*)x_raw;
    for (int i = gid; i < nX; i += stride) xbf[i] = src[i];
  } else {
    const float* src = (const float*)x_raw;
    for (int i = gid; i < nX; i += stride) xbf[i] = f2bbits(src[i]);
  }
  // b1 stored PERMUTED: wts[1024 + p] = b1[c_nat(p)]
  for (int i = gid; i < 512;  i += stride) {
    int hp = i >> 7, l16 = (i >> 3) & 15, nt = i & 7;
    int c = hp * 128 + nt * 16 + l16;
    wts[1024 + i] = CVT(b1r, c);
  }
  for (int i = gid; i < 64;   i += stride) wts[1536 + i] = CVT(as2r, i);
  for (int i = gid; i < 64;   i += stride) wts[1600 + i] = CVT(ad2r, i);
  for (int i = gid; i < 64;   i += stride) wts[1664 + i] = CVT(b2r, i);
  for (int i = gid; i < 4096; i += stride) wts[1728 + i] = CVT(l1wr, i);
  for (int i = gid; i < 64;   i += stride) wts[5824 + i] = CVT(l1br, i);
  for (int i = gid; i < 640;  i += stride) wts[5888 + i] = CVT(l2wr, i);
  for (int i = gid; i < 10;   i += stride) wts[6528 + i] = CVT(l2br, i);
  // W1frag NATURAL k
  for (int t = gid; t < 8192; t += stride) {
    int lane = t & 63, ks = (t >> 6) & 3, nt = t >> 8;
    for (int j = 0; j < 8; ++j) {
      int k = ks * 32 + (lane >> 4) * 8 + j;
      int n = nt * 16 + (lane & 15);
      w1frag[t * 8 + j] = f2bbits(CVT(w1raw, k * 512 + n));
    }
  }
  // W2frag with PERMUTED k: k index in fragment = position p; fetch W2[c_nat(p)]
  for (int t = gid; t < 4096; t += stride) {
    int lane = t & 63, nt = (t >> 6) & 3, ks = t >> 8;
    for (int j = 0; j < 8; ++j) {
      int p = ks * 32 + (lane >> 4) * 8 + j;          // permuted position
      int hp = p >> 7, pl16 = (p >> 3) & 15, pnt = p & 7;
      int k = hp * 128 + pnt * 16 + pl16;             // natural channel
      int n = nt * 16 + (lane & 15);
      w2frag[t * 8 + j] = f2bbits(CVT(w2raw, k * 64 + n));
    }
  }
  // Vfrag: B-fragment of V[128 x 16], V[:,n<8] = W1 head-n col @ att_src[n],
  // V[:,n>=8] = same with att_dst. a_s/a_d = x @ V.
  for (int t = gid; t < 2048; t += stride) {
    int j = t & 7, lane = (t >> 3) & 63, ks = t >> 9;
    int k = ks * 32 + (lane >> 4) * 8 + j;
    int n = lane & 15;
    int hh = (n < 8) ? n : (n - 8);
    float s = 0.f;
    if (n < 8) {
      for (int c = 0; c < 64; ++c)
        s += CVT(w1raw, k * 512 + hh * 64 + c) * CVT(as1r, hh * 64 + c);
    } else {
      for (int c = 0; c < 64; ++c)
        s += CVT(w1raw, k * 512 + hh * 64 + c) * CVT(ad1r, hh * 64 + c);
    }
    vfrag[(ks * 64 + lane) * 8 + j] = f2bbits(s);
  }
  for (int i = gid; i < N; i += stride) deg[i] = 0;
  for (int i = gid; i < N * 8; i += stride) dng[i] = 0.f;
  for (int i = gid; i < B * C; i += stride) pooled[i] = 0.f;
}

// ---------- degree count ----------
__global__ void deg_count_kernel(const int* __restrict__ ei, int E, int Etot,
                                 int* __restrict__ deg) {
  int e = blockIdx.x * blockDim.x + threadIdx.x;
  if (e >= Etot) return;
  int d = (e < E) ? ei[E + e] : e - E;
  atomicAdd(&deg[d], 1);
}

// ---------- CSR scans ----------
__global__ void scan_block_kernel(const int* __restrict__ deg,
                                  int* __restrict__ local,
                                  int* __restrict__ bsum, int N) {
  __shared__ int tmp[256];
  int t = threadIdx.x;
  int i = blockIdx.x * 256 + t;
  int v = (i < N) ? deg[i] : 0;
  tmp[t] = v;
  __syncthreads();
  for (int off = 1; off < 256; off <<= 1) {
    int u = (t >= off) ? tmp[t - off] : 0;
    __syncthreads();
    tmp[t] += u;
    __syncthreads();
  }
  if (i < N) local[i] = tmp[t] - v;
  if (t == 255) bsum[blockIdx.x] = tmp[255];
}

__global__ void scan_finish_kernel(const int* __restrict__ local,
                                   const int* __restrict__ bsum, int nb,
                                   int* __restrict__ rowptr,
                                   int* __restrict__ cursor, int N, int Etot) {
  __shared__ int tmp[256];
  __shared__ int offs;
  int t = threadIdx.x;
  int v0 = (t < nb) ? bsum[t] : 0;
  tmp[t] = v0;
  __syncthreads();
  for (int off = 1; off < 256; off <<= 1) {
    int u = (t >= off) ? tmp[t - off] : 0;
    __syncthreads();
    tmp[t] += u;
    __syncthreads();
  }
  if (t == (int)blockIdx.x) offs = tmp[t] - v0;
  __syncthreads();
  int i = blockIdx.x * 256 + t;
  if (i < N) {
    int r = local[i] + offs;
    rowptr[i] = r;
    cursor[i] = r;
  }
  if (i == 0) rowptr[N] = Etot;
}

// ---------- attention scalars: a_s/a_d = x @ V  (4 MFMA per 16 rows) ----------
__global__ __launch_bounds__(256) void att_scalars_kernel(
    const unsigned short* __restrict__ xbf,     // N x 128 bf16
    const unsigned short* __restrict__ vfrag,   // [4ks][64][8] bf16
    float* __restrict__ a_s, float* __restrict__ a_d,   // N x 8
    int N) {
  int t = threadIdx.x, w = t >> 6, lane = t & 63;
  int quad = lane >> 4, l16 = lane & 15;
  int row0 = blockIdx.x * 64 + w * 16;

  floatx4 acc = {};
  int rl = row0 + l16; if (rl >= N) rl = N - 1;
  const unsigned short* xp = xbf + (size_t)rl * 128 + quad * 8;
#pragma unroll
  for (int ks = 0; ks < 4; ++ks) {
    short8 a = *(const short8*)(xp + ks * 32);
    short8 b = *(const short8*)&vfrag[(ks * 64 + lane) * 8];
    acc = __builtin_amdgcn_mfma_f32_16x16x32_bf16(a, b, acc, 0, 0, 0);
  }
#pragma unroll
  for (int r = 0; r < 4; ++r) {
    int row = row0 + quad * 4 + r;
    if (row < N) {
      if (l16 < 8) a_s[(size_t)row * 8 + l16] = acc[r];
      else         a_d[(size_t)row * 8 + (l16 - 8)] = acc[r];
    }
  }
}

// ---------- CSR fill + per-edge softmax weights (bf16 x8, CSR slot order) ----
// col[pos] = src | (dest&15)<<27. Also accumulates the per-dest softmax
// denominator DN[d][h] = sum of bf16-rounded weights (global atomics).
__global__ void fill_weight_kernel(const int* __restrict__ ei, int E, int Etot,
                                   const float* __restrict__ a_s,
                                   const float* __restrict__ a_d,
                                   int* __restrict__ cursor,
                                   int* __restrict__ col,
                                   unsigned short* __restrict__ wedge,
                                   float* __restrict__ dng) {
  int e = blockIdx.x * 256 + threadIdx.x;
  if (e >= Etot) return;
  int s, d;
  if (e < E) { s = ei[e]; d = ei[E + e]; } else { s = d = e - E; }
  int pos = atomicAdd(&cursor[d], 1);
  col[pos] = s | ((d & 15) << 27);
  float4 s0 = *(const float4*)(a_s + (size_t)s * 8);
  float4 s1 = *(const float4*)(a_s + (size_t)s * 8 + 4);
  float4 d0 = *(const float4*)(a_d + (size_t)d * 8);
  float4 d1 = *(const float4*)(a_d + (size_t)d * 8 + 4);
  float v, w0, w1, w2, w3, w4, w5, w6, w7;
  v = s0.x + d0.x; v = v > 0.f ? v : NEG * v; w0 = __expf(v);
  v = s0.y + d0.y; v = v > 0.f ? v : NEG * v; w1 = __expf(v);
  v = s0.z + d0.z; v = v > 0.f ? v : NEG * v; w2 = __expf(v);
  v = s0.w + d0.w; v = v > 0.f ? v : NEG * v; w3 = __expf(v);
  v = s1.x + d1.x; v = v > 0.f ? v : NEG * v; w4 = __expf(v);
  v = s1.y + d1.y; v = v > 0.f ? v : NEG * v; w5 = __expf(v);
  v = s1.z + d1.z; v = v > 0.f ? v : NEG * v; w6 = __expf(v);
  v = s1.w + d1.w; v = v > 0.f ? v : NEG * v; w7 = __expf(v);
  uint4 o;
  o.x = pack2(w0, w1); o.y = pack2(w2, w3);
  o.z = pack2(w4, w5); o.w = pack2(w6, w7);
  *(uint4*)(wedge + (size_t)pos * 8) = o;
  float* dp = dng + (size_t)d * 8;
  unsafeAtomicAdd(dp + 0, blo(o.x));
  unsafeAtomicAdd(dp + 1, bhi(o.x));
  unsafeAtomicAdd(dp + 2, blo(o.y));
  unsafeAtomicAdd(dp + 3, bhi(o.y));
  unsafeAtomicAdd(dp + 4, blo(o.z));
  unsafeAtomicAdd(dp + 5, bhi(o.z));
  unsafeAtomicAdd(dp + 6, blo(o.w));
  unsafeAtomicAdd(dp + 7, bhi(o.w));
}

// ---------- MFMA-based x-space aggregation + W1 GEMM -> out1 ----------
// Block = 512 threads (8 waves), TILE = 16 dests, chunks of 32 edge slots:
//   stage XgT[128f][32k] bf16: paired-b32 writes, per-pair XOR swizzle
//   build Wm[8h][16d][32k] bf16 masked weights (dl pre-packed in col bits 27+)
//   wave h: accw[ft] += MFMA(Wm[h], XgT[ft])   (denominator comes from dng)
// LDS: {XgT 8K + Wm 8K} UNION {AggP 34.8K}. launch_bounds(512,6): 3 blocks/CU,
// VGPR budget 85 — no spills (round-6 lesson: (512,8) forced 190MB of scratch).
__global__ __launch_bounds__(512, 6) void aggx_gemm1_kernel(
    const unsigned short* __restrict__ xbf,     // N x 128 bf16
    const unsigned short* __restrict__ W1frag,  // [32][4][64][8] bf16 (natural k)
    const int* __restrict__ rowptr,
    const int* __restrict__ col,                // src | dl<<27
    const unsigned short* __restrict__ wedge,   // Etot x 8 bf16 (CSR order)
    const float* __restrict__ dng,              // N x 8 f32 denominators
    const float* __restrict__ bias_perm,        // 512, PERMUTED
    unsigned short* __restrict__ out1,          // N x 512 bf16 (PERMUTED)
    int N) {
  __shared__ __align__(16) char LB[8 * 16 * 136 * 2];   // 34816 B union
  unsigned short* XgT = (unsigned short*)LB;            // 8 KB (chunk loop)
  unsigned short* Wm  = (unsigned short*)(LB + 8192);   // 8 KB (chunk loop)
  unsigned short* AggP = (unsigned short*)LB;           // 34.8 KB (epilogue)

  int t = threadIdx.x, w = t >> 6, lane = t & 63;
  int q = lane >> 4, n = lane & 15;
  int dbase = blockIdx.x * 16;

  int R0 = rowptr[dbase];
  int R1 = rowptr[min(dbase + 16, N)];
  int nch = (R1 - R0 + 31) >> 5;

  // staging ids: kp = edge-pair (0..15), pp = feature-quad (0..31)
  int kp = t >> 5, pp = t & 31;
  int skey = ((pp >> 1) & 7) << 4;       // = ((f>>3)&7)<<4 for f = 4*pp+df
  // wmat ids
  int dw = t >> 5, kw = t & 31;

  floatx4 accw[8] = {};

  for (int c = 0; c < nch; ++c) {
    int ebase = R0 + c * 32;
    __syncthreads();                       // prior chunk's MFMA reads done

    // ---- stage XgT: element (f,k) at byte (64f + 2k) ^ ((f>>3&7)<<4).
    // Thread handles edges 2kp, 2kp+1 x features 4pp..4pp+3; the two k
    // elements of one f share a dword -> 4 b32 writes (key bits 4-6 never
    // touch bits 0-1, so pairs stay adjacent after XOR).
    {
      int e0 = ebase + 2 * kp;
      int ec0 = (e0 < R1) ? e0 : (R1 - 1);
      int ec1 = (e0 + 1 < R1) ? (e0 + 1) : (R1 - 1);
      int s0 = col[ec0] & SMASK;
      int s1 = col[ec1] & SMASK;
      uint2 xa = *(const uint2*)(xbf + (size_t)s0 * 128 + pp * 4);
      uint2 xb = *(const uint2*)(xbf + (size_t)s1 * 128 + pp * 4);
      int base = 256 * pp + 4 * kp;        // byte addr of (f=4pp, k=2kp)
      unsigned w0 = (xa.x & 0xffffu) | (xb.x << 16);
      unsigned w1 = (xa.x >> 16) | (xb.x & 0xffff0000u);
      unsigned w2 = (xa.y & 0xffffu) | (xb.y << 16);
      unsigned w3 = (xa.y >> 16) | (xb.y & 0xffff0000u);
      *(unsigned*)((char*)XgT + ((base)       ^ skey)) = w0;
      *(unsigned*)((char*)XgT + ((base + 64)  ^ skey)) = w1;
      *(unsigned*)((char*)XgT + ((base + 128) ^ skey)) = w2;
      *(unsigned*)((char*)XgT + ((base + 192) ^ skey)) = w3;
    }
    // ---- build Wm: dl pre-packed in col, weights already bf16 ----
    {
      int ew = ebase + kw;
      bool evw = ew < R1;
      int ewc = evw ? ew : (R1 - 1);
      int cv = col[ewc];
      int dl = (cv >> 27) & 15;
      uint4 wv = *(const uint4*)(wedge + (size_t)ewc * 8);
      bool mine = evw && (dl == dw);
      unsigned short* wmp = Wm + dw * 32 + kw;
      wmp[0]    = mine ? (unsigned short)(wv.x & 0xffff) : 0;
      wmp[512]  = mine ? (unsigned short)(wv.x >> 16)    : 0;
      wmp[1024] = mine ? (unsigned short)(wv.y & 0xffff) : 0;
      wmp[1536] = mine ? (unsigned short)(wv.y >> 16)    : 0;
      wmp[2048] = mine ? (unsigned short)(wv.z & 0xffff) : 0;
      wmp[2560] = mine ? (unsigned short)(wv.z >> 16)    : 0;
      wmp[3072] = mine ? (unsigned short)(wv.w & 0xffff) : 0;
      wmp[3584] = mine ? (unsigned short)(wv.w >> 16)    : 0;
    }
    __syncthreads();

    // ---- MFMA: wave w = head w ----
    short8 af = *(const short8*)(Wm + w * 512 + n * 32 + 8 * q);
#pragma unroll
    for (int ft = 0; ft < 8; ++ft) {
      int bb = (ft * 16 + n) * 64 + 16 * q;
      bb ^= ((bb >> 9) & 7) << 4;
      short8 bfr = *(const short8*)((const char*)XgT + bb);
      accw[ft] = __builtin_amdgcn_mfma_f32_16x16x32_bf16(af, bfr, accw[ft], 0, 0, 0);
    }
  }

  __syncthreads();                         // last MFMA reads done before AggP

  // ---- epilogue: normalize (denominators from global), write AggP bf16 ----
  {
    float dnv[4];
#pragma unroll
    for (int r = 0; r < 4; ++r) {
      int row = dbase + 4 * q + r;
      int rc = row < N ? row : N - 1;
      dnv[r] = rcp_nr(dng[(size_t)rc * 8 + w] + 1e-16f);
    }
#pragma unroll
    for (int ft = 0; ft < 8; ++ft)
#pragma unroll
      for (int r = 0; r < 4; ++r)
        AggP[w * 2176 + (4 * q + r) * 136 + ft * 16 + n] =
            f2bbits(accw[ft][r] * dnv[r]);
  }
  __syncthreads();

  // ---- phase 3: per-head W1 GEMM, bias + ELU, permuted store ----
  {
    int hp = w >> 1, qq = w & 1;
    floatx4 acc2[4] = {};
    const unsigned short* Bp = W1frag + (size_t)hp * 16384;
#pragma unroll
    for (int ks = 0; ks < 4; ++ks) {
      short8 a2 = *(const short8*)&AggP[w * 2176 + n * 136 + ks * 32 + q * 8];
#pragma unroll
      for (int j = 0; j < 4; ++j) {
        int nt = qq * 4 + j;
        short8 b2 = *(const short8*)&Bp[((nt * 4 + ks) * 64 + lane) * 8];
        acc2[j] = __builtin_amdgcn_mfma_f32_16x16x32_bf16(a2, b2, acc2[j], 0, 0, 0);
      }
    }
    float4 bq = *(const float4*)&bias_perm[hp * 128 + n * 8 + qq * 4];
#pragma unroll
    for (int r = 0; r < 4; ++r) {
      int row = dbase + 4 * q + r;
      if (row < N) {
        uint2 o;
        o.x = pack2(elu1(acc2[0][r] + bq.x), elu1(acc2[1][r] + bq.y));
        o.y = pack2(elu1(acc2[2][r] + bq.z), elu1(acc2[3][r] + bq.w));
        *(uint2*)&out1[(size_t)row * 512 + hp * 128 + n * 8 + qq * 4] = o;
      }
    }
  }
}

// ---------- layer 2: MFMA bf16 GEMM (k-dim permuted to match out1bf) ----------
__global__ __launch_bounds__(256) void gemm2_mfma_kernel(
    const unsigned short* __restrict__ x2bf,    // N x 512 bf16 (PERMUTED k)
    const unsigned short* __restrict__ W2frag,  // [16ks][4nt][64][8] bf16 (perm k)
    const float* __restrict__ att_src,          // 64
    const float* __restrict__ att_dst,
    unsigned short* __restrict__ h2,            // N x 64 bf16 (natural)
    float* __restrict__ a_s, float* __restrict__ a_d,  // N
    int N) {
  int t = threadIdx.x;
  int w = t >> 6, lane = t & 63;
  int quad = lane >> 4, l16 = lane & 15;
  int rowbase = blockIdx.x * 64 + w * 16;

  floatx4 acc[4] = {};
  int r0 = rowbase + l16; if (r0 >= N) r0 = N - 1;
  const unsigned short* p0 = x2bf + (size_t)r0 * 512 + quad * 8;
#pragma unroll
  for (int ks = 0; ks < 16; ++ks) {
    short8 a0 = *(const short8*)(p0 + ks * 32);
#pragma unroll
    for (int nt = 0; nt < 4; ++nt) {
      short8 b = *(const short8*)&W2frag[((ks * 4 + nt) * 64 + lane) * 8];
      acc[nt] = __builtin_amdgcn_mfma_f32_16x16x32_bf16(a0, b, acc[nt], 0, 0, 0);
    }
  }

  float asw[4], adw[4];
#pragma unroll
  for (int nt = 0; nt < 4; ++nt) {
    asw[nt] = att_src[nt * 16 + l16];
    adw[nt] = att_dst[nt * 16 + l16];
  }
  float ps[4] = {}, pd[4] = {};
#pragma unroll
  for (int nt = 0; nt < 4; ++nt)
#pragma unroll
    for (int r = 0; r < 4; ++r) {
      float v = acc[nt][r];
      int row = rowbase + quad * 4 + r;
      if (row < N) h2[(size_t)row * 64 + nt * 16 + l16] = f2bbits(v);
      ps[r] += v * asw[nt];
      pd[r] += v * adw[nt];
    }
#pragma unroll
  for (int r = 0; r < 4; ++r) {
    float p = ps[r], q = pd[r];
#pragma unroll
    for (int off = 1; off < 16; off <<= 1) {
      p += __shfl_xor(p, off);
      q += __shfl_xor(q, off);
    }
    int row = rowbase + quad * 4 + r;
    if (l16 == 0 && row < N) {
      a_s[row] = p;
      a_d[row] = q;
    }
  }
}

// H=1, quarter-wave edge grouping (h2 natural layout).
__global__ void gat_agg1_kernel(const int* __restrict__ rowptr,
                                const int* __restrict__ col,
                                const float* __restrict__ a_s,
                                const float* __restrict__ a_d,
                                const unsigned short* __restrict__ hfeat,
                                const float* __restrict__ bias,
                                unsigned short* __restrict__ out, int N) {
  int wave = threadIdx.x >> 6, lane = threadIdx.x & 63;
  int d = blockIdx.x * 4 + wave;
  if (d >= N) return;
  int beg = rowptr[d], end = rowptr[d + 1];
  int qg = lane >> 4, l16 = lane & 15;
  float adv = a_d[d];
  const uint2* hfu = (const uint2*)hfeat;
  float acc[4] = {};
  float wsum = 0.f;
#pragma unroll 2
  for (int i = beg + qg; i < end; i += 4) {
    int s = col[i] & SMASK;
    float v = a_s[s] + adv;
    v = v > 0.f ? v : NEG * v;
    float wv = __expf(v);
    wsum += wv;
    uint2 u = hfu[(size_t)s * 16 + l16];
    acc[0] += wv * blo(u.x); acc[1] += wv * bhi(u.x);
    acc[2] += wv * blo(u.y); acc[3] += wv * bhi(u.y);
  }
#pragma unroll
  for (int off = 16; off <= 32; off <<= 1) {
#pragma unroll
    for (int j = 0; j < 4; ++j) acc[j] += __shfl_xor(acc[j], off);
    wsum += __shfl_xor(wsum, off);
  }
  float winv = 1.f / (wsum + 1e-16f);
  float4 bb = ((const float4*)bias)[l16];
  float r0 = elu1(acc[0] * winv + bb.x), r1 = elu1(acc[1] * winv + bb.y);
  float r2 = elu1(acc[2] * winv + bb.z), r3 = elu1(acc[3] * winv + bb.w);
  if (qg == 0) {
    uint2 o; o.x = pack2(r0, r1); o.y = pack2(r2, r3);
    ((uint2*)out)[(size_t)d * 16 + l16] = o;
  }
}

// ---------- pooling: 16 nodes per wave ----------
__global__ void pool_kernel(const unsigned short* __restrict__ out2,
                            const int* __restrict__ batch,
                            float* __restrict__ pooled, int N) {
  int wave = threadIdx.x >> 6, lane = threadIdx.x & 63;
  int seg = blockIdx.x * 4 + wave;
  int start = seg * 16;
  if (start >= N) return;
  int end = min(start + 16, N);
  int cur = batch[start];
  float acc = 0.f;
  for (int n = start; n < end; ++n) {
    int bn = batch[n];
    if (bn != cur) {
      unsafeAtomicAdd(&pooled[cur * 64 + lane], acc);
      acc = 0.f; cur = bn;
    }
    acc += bu(out2[(size_t)n * 64 + lane]);
  }
  unsafeAtomicAdd(&pooled[cur * 64 + lane], acc);
}

// ---------- MLP head + log_softmax: one block (one wave) per graph ----------
__global__ void head_kernel(const float* __restrict__ pooled,
                            const float* __restrict__ lin1_w,
                            const float* __restrict__ lin1_b,
                            const float* __restrict__ lin2_w,
                            const float* __restrict__ lin2_b,
                            const void* __restrict__ x_raw,
                            void* __restrict__ outv) {
  __shared__ float P[C];
  __shared__ float Zs[C];
  __shared__ float Ls[K];
  __shared__ float lse_s;
  __shared__ int fl;
  int isbf = detect_dev(x_raw, &fl);
  int g = blockIdx.x, t = threadIdx.x;   // 64 threads
  P[t] = pooled[g * C + t];
  __syncthreads();
  float acc = lin1_b[t];
  for (int k = 0; k < C; ++k) acc += P[k] * lin1_w[k * C + t];
  Zs[t] = elu1(acc);
  __syncthreads();
  if (t < K) {
    float a = lin2_b[t];
    for (int k = 0; k < C; ++k) a += Zs[k] * lin2_w[k * K + t];
    Ls[t] = a;
  }
  __syncthreads();
  if (t == 0) {
    float mx = -1e30f;
    for (int c = 0; c < K; ++c) mx = fmaxf(mx, Ls[c]);
    float s = 0.f;
    for (int c = 0; c < K; ++c) s += __expf(Ls[c] - mx);
    lse_s = mx + __logf(s);
  }
  __syncthreads();
  if (t < K) {
    float val = Ls[t] - lse_s;
    if (isbf) ((__hip_bfloat16*)outv)[g * K + t] = __float2bfloat16(val);
    else      ((float*)outv)[g * K + t] = val;
  }
}

extern "C" void kernel_launch(void* const* d_in, const int* in_sizes, int n_in,
                              void* d_out, int out_size, void* d_ws, size_t ws_size,
                              hipStream_t stream) {
  const void* x_raw = d_in[0];
  const int*  ei    = (const int*)d_in[1];
  const int*  batch = (const int*)d_in[2];

  const int N    = in_sizes[2];
  const int E    = in_sizes[1] / 2;
  const int Etot = E + N;
  const int nb   = (N + 255) / 256;

  float* ws   = (float*)d_ws;
  size_t off  = 0;

  float* wts = ws + off; off += 6544;
  float* b1w  = wts + 1024;
  float* as2w = wts + 1536;
  float* ad2w = wts + 1600;
  float* b2w  = wts + 1664;
  float* l1w  = wts + 1728;
  float* l1b  = wts + 5824;
  float* l2w  = wts + 5888;
  float* l2b  = wts + 6528;

  unsigned short* xbf    = (unsigned short*)(ws + off); off += (size_t)N * 64;
  unsigned short* w1frag = (unsigned short*)(ws + off); off += 32768;
  unsigned short* w2frag = (unsigned short*)(ws + off); off += 16384;
  unsigned short* vfrag  = (unsigned short*)(ws + off); off += 1024;
  unsigned short* wedge  = (unsigned short*)(ws + off); off += (size_t)Etot * 4;
  unsigned short* out1bf = (unsigned short*)(ws + off); off += (size_t)N * 256;
  unsigned short* h2bf   = (unsigned short*)(ws + off); off += (size_t)N * 32;
  unsigned short* out2bf = (unsigned short*)(ws + off); off += (size_t)N * 32;
  float* as1  = ws + off; off += (size_t)N * H1;
  float* ad1  = ws + off; off += (size_t)N * H1;
  float* dng  = ws + off; off += (size_t)N * H1;
  float* as2  = ws + off; off += (size_t)N;
  float* ad2  = ws + off; off += (size_t)N;
  float* pooled = ws + off; off += (size_t)B * C;

  int* ibase  = (int*)(ws + off);
  int* deg    = ibase;                 ibase += N;
  int* cursor = ibase;                 ibase += N;
  int* rowptr = ibase;                 ibase += N + 1;
  int* locals = ibase;                 ibase += N;
  int* bsum   = ibase;                 ibase += 256;
  int* col    = ibase;                 ibase += Etot;

  // ---- prep ----
  fused_prep_kernel<<<1024, 256, 0, stream>>>(
      x_raw, d_in[3], d_in[4], d_in[5], d_in[6], d_in[7], d_in[8], d_in[9],
      d_in[10], d_in[11], d_in[12], d_in[13], d_in[14],
      xbf, w1frag, w2frag, vfrag, wts, deg, pooled, dng, in_sizes[0], N);

  // ---- CSR: deg + scans ----
  deg_count_kernel<<<(Etot + 255) / 256, 256, 0, stream>>>(ei, E, Etot, deg);
  scan_block_kernel<<<nb, 256, 0, stream>>>(deg, locals, bsum, N);
  scan_finish_kernel<<<nb, 256, 0, stream>>>(locals, bsum, nb, rowptr, cursor, N, Etot);

  // ---- layer-1 attention scalars via factored V (tiny MFMA GEMM) ----
  att_scalars_kernel<<<(N + 63) / 64, 256, 0, stream>>>(xbf, vfrag, as1, ad1, N);

  // ---- CSR fill + per-edge softmax weights (bf16) + denominators ----
  fill_weight_kernel<<<(Etot + 255) / 256, 256, 0, stream>>>(
      ei, E, Etot, as1, ad1, cursor, col, wedge, dng);

  // ---- MFMA x-space aggregation + W1 GEMM -> out1 ----
  aggx_gemm1_kernel<<<(N + 15) / 16, 512, 0, stream>>>(
      xbf, w1frag, rowptr, col, wedge, dng, b1w, out1bf, N);

  // ---- layer 2 ----
  gemm2_mfma_kernel<<<(N + 63) / 64, 256, 0, stream>>>(out1bf, w2frag, as2w, ad2w,
                                                       h2bf, as2, ad2, N);
  gat_agg1_kernel<<<(N + 3) / 4, 256, 0, stream>>>(rowptr, col, as2, ad2, h2bf, b2w, out2bf, N);

  // ---- pool + head ----
  pool_kernel<<<(N + 63) / 64, 256, 0, stream>>>(out2bf, batch, pooled, N);
  head_kernel<<<B, 64, 0, stream>>>(pooled, l1w, l1b, l2w, l2b, x_raw, (void*)d_out);
}

// Round 8
// 295.962 us; speedup vs baseline: 1.5606x; 1.5606x over previous
//
#include <hip/hip_runtime.h>
#include <hip/hip_bf16.h>

#define DEV static __device__ __forceinline__

constexpr int F1 = 128;   // input features
constexpr int H1 = 8;     // heads layer1
constexpr int C  = 64;    // channels per head
constexpr int B  = 64;    // graphs
constexpr int K  = 10;    // classes
constexpr float NEG = 0.2f;
constexpr unsigned SMASK = 0x07FFFFFFu;   // col[] low bits = src id; bits 27-30 = dest&15

typedef __attribute__((ext_vector_type(8))) short short8;
typedef __attribute__((ext_vector_type(4))) float floatx4;

DEV float b2f(__hip_bfloat16 x) { return __bfloat162float(x); }
DEV float elu1(float v) { return v > 0.f ? v : (__expf(v) - 1.f); }
DEV unsigned short f2bbits(float f) {
  __hip_bfloat16 b = __float2bfloat16(f);
  return *(unsigned short*)&b;
}
DEV float blo(unsigned u) { return __uint_as_float(u << 16); }
DEV float bhi(unsigned u) { return __uint_as_float(u & 0xffff0000u); }
DEV float bu(unsigned short u) { return __uint_as_float(((unsigned)u) << 16); }
DEV unsigned pack2(float lo, float hi) {
  return (unsigned)f2bbits(lo) | ((unsigned)f2bbits(hi) << 16);
}
// 1/x via v_rcp_f32 + one Newton step
DEV float rcp_nr(float x) {
  float r = __builtin_amdgcn_rcpf(x);
  return r * (2.f - x * r);
}

// out1 PERMUTED layout: position p = hp*128 + l16*8 + nt  <->  natural channel
// c = hp*128 + nt*16 + l16. W2frag k-rows and b1 permuted to match.
// W1frag k is NATURAL.

// Self-detection: thread 0 samples 128 even-index bf16 reinterps of x.
DEV int detect_dev(const void* xraw, int* lds) {
  if (threadIdx.x == 0) {
    const __hip_bfloat16* xb = (const __hip_bfloat16*)xraw;
    int bad = 0;
    for (int i = 0; i < 128; ++i) {
      float v = b2f(xb[2 * i]);
      if (!(fabsf(v) < 1e4f)) bad++;
    }
    *lds = (bad < 13) ? 1 : 0;     // 1 = bf16, 0 = f32
  }
  __syncthreads();
  return *lds;
}

#define CVT(p, i) (isbf ? b2f(((const __hip_bfloat16*)(p))[i]) : ((const float*)(p))[i])

// ---------- fused prep ----------
__global__ void fused_prep_kernel(const void* x_raw, const void* w1raw,
                                  const void* as1r, const void* ad1r, const void* b1r,
                                  const void* w2raw,
                                  const void* as2r, const void* ad2r, const void* b2r,
                                  const void* l1wr, const void* l1br,
                                  const void* l2wr, const void* l2br,
                                  unsigned short* __restrict__ xbf,
                                  unsigned short* __restrict__ w1frag,
                                  unsigned short* __restrict__ w2frag,
                                  unsigned short* __restrict__ vfrag,
                                  float* __restrict__ wts,
                                  int* __restrict__ deg,
                                  float* __restrict__ pooled,
                                  int nX, int N) {
  __shared__ int fl;
  int isbf = detect_dev(x_raw, &fl);
  int gid = blockIdx.x * 256 + threadIdx.x;
  int stride = gridDim.x * 256;

  if (isbf) {
    const unsigned short* src = (const unsigned short*)x_raw;
    for (int i = gid; i < nX; i += stride) xbf[i] = src[i];
  } else {
    const float* src = (const float*)x_raw;
    for (int i = gid; i < nX; i += stride) xbf[i] = f2bbits(src[i]);
  }
  // b1 stored PERMUTED: wts[1024 + p] = b1[c_nat(p)]
  for (int i = gid; i < 512;  i += stride) {
    int hp = i >> 7, l16 = (i >> 3) & 15, nt = i & 7;
    int c = hp * 128 + nt * 16 + l16;
    wts[1024 + i] = CVT(b1r, c);
  }
  for (int i = gid; i < 64;   i += stride) wts[1536 + i] = CVT(as2r, i);
  for (int i = gid; i < 64;   i += stride) wts[1600 + i] = CVT(ad2r, i);
  for (int i = gid; i < 64;   i += stride) wts[1664 + i] = CVT(b2r, i);
  for (int i = gid; i < 4096; i += stride) wts[1728 + i] = CVT(l1wr, i);
  for (int i = gid; i < 64;   i += stride) wts[5824 + i] = CVT(l1br, i);
  for (int i = gid; i < 640;  i += stride) wts[5888 + i] = CVT(l2wr, i);
  for (int i = gid; i < 10;   i += stride) wts[6528 + i] = CVT(l2br, i);
  // W1frag NATURAL k
  for (int t = gid; t < 8192; t += stride) {
    int lane = t & 63, ks = (t >> 6) & 3, nt = t >> 8;
    for (int j = 0; j < 8; ++j) {
      int k = ks * 32 + (lane >> 4) * 8 + j;
      int n = nt * 16 + (lane & 15);
      w1frag[t * 8 + j] = f2bbits(CVT(w1raw, k * 512 + n));
    }
  }
  // W2frag with PERMUTED k: k index in fragment = position p; fetch W2[c_nat(p)]
  for (int t = gid; t < 4096; t += stride) {
    int lane = t & 63, nt = (t >> 6) & 3, ks = t >> 8;
    for (int j = 0; j < 8; ++j) {
      int p = ks * 32 + (lane >> 4) * 8 + j;          // permuted position
      int hp = p >> 7, pl16 = (p >> 3) & 15, pnt = p & 7;
      int k = hp * 128 + pnt * 16 + pl16;             // natural channel
      int n = nt * 16 + (lane & 15);
      w2frag[t * 8 + j] = f2bbits(CVT(w2raw, k * 64 + n));
    }
  }
  // Vfrag: B-fragment of V[128 x 16], V[:,n<8] = W1 head-n col @ att_src[n],
  // V[:,n>=8] = same with att_dst. a_s/a_d = x @ V.
  for (int t = gid; t < 2048; t += stride) {
    int j = t & 7, lane = (t >> 3) & 63, ks = t >> 9;
    int k = ks * 32 + (lane >> 4) * 8 + j;
    int n = lane & 15;
    int hh = (n < 8) ? n : (n - 8);
    float s = 0.f;
    if (n < 8) {
      for (int c = 0; c < 64; ++c)
        s += CVT(w1raw, k * 512 + hh * 64 + c) * CVT(as1r, hh * 64 + c);
    } else {
      for (int c = 0; c < 64; ++c)
        s += CVT(w1raw, k * 512 + hh * 64 + c) * CVT(ad1r, hh * 64 + c);
    }
    vfrag[(ks * 64 + lane) * 8 + j] = f2bbits(s);
  }
  for (int i = gid; i < N; i += stride) deg[i] = 0;
  for (int i = gid; i < B * C; i += stride) pooled[i] = 0.f;
}

// ---------- degree count ----------
__global__ void deg_count_kernel(const int* __restrict__ ei, int E, int Etot,
                                 int* __restrict__ deg) {
  int e = blockIdx.x * blockDim.x + threadIdx.x;
  if (e >= Etot) return;
  int d = (e < E) ? ei[E + e] : e - E;
  atomicAdd(&deg[d], 1);
}

// ---------- CSR scans ----------
__global__ void scan_block_kernel(const int* __restrict__ deg,
                                  int* __restrict__ local,
                                  int* __restrict__ bsum, int N) {
  __shared__ int tmp[256];
  int t = threadIdx.x;
  int i = blockIdx.x * 256 + t;
  int v = (i < N) ? deg[i] : 0;
  tmp[t] = v;
  __syncthreads();
  for (int off = 1; off < 256; off <<= 1) {
    int u = (t >= off) ? tmp[t - off] : 0;
    __syncthreads();
    tmp[t] += u;
    __syncthreads();
  }
  if (i < N) local[i] = tmp[t] - v;
  if (t == 255) bsum[blockIdx.x] = tmp[255];
}

__global__ void scan_finish_kernel(const int* __restrict__ local,
                                   const int* __restrict__ bsum, int nb,
                                   int* __restrict__ rowptr,
                                   int* __restrict__ cursor, int N, int Etot) {
  __shared__ int tmp[256];
  __shared__ int offs;
  int t = threadIdx.x;
  int v0 = (t < nb) ? bsum[t] : 0;
  tmp[t] = v0;
  __syncthreads();
  for (int off = 1; off < 256; off <<= 1) {
    int u = (t >= off) ? tmp[t - off] : 0;
    __syncthreads();
    tmp[t] += u;
    __syncthreads();
  }
  if (t == (int)blockIdx.x) offs = tmp[t] - v0;
  __syncthreads();
  int i = blockIdx.x * 256 + t;
  if (i < N) {
    int r = local[i] + offs;
    rowptr[i] = r;
    cursor[i] = r;
  }
  if (i == 0) rowptr[N] = Etot;
}

// ---------- attention scalars: a_s/a_d = x @ V  (4 MFMA per 16 rows) ----------
__global__ __launch_bounds__(256) void att_scalars_kernel(
    const unsigned short* __restrict__ xbf,     // N x 128 bf16
    const unsigned short* __restrict__ vfrag,   // [4ks][64][8] bf16
    float* __restrict__ a_s, float* __restrict__ a_d,   // N x 8
    int N) {
  int t = threadIdx.x, w = t >> 6, lane = t & 63;
  int quad = lane >> 4, l16 = lane & 15;
  int row0 = blockIdx.x * 64 + w * 16;

  floatx4 acc = {};
  int rl = row0 + l16; if (rl >= N) rl = N - 1;
  const unsigned short* xp = xbf + (size_t)rl * 128 + quad * 8;
#pragma unroll
  for (int ks = 0; ks < 4; ++ks) {
    short8 a = *(const short8*)(xp + ks * 32);
    short8 b = *(const short8*)&vfrag[(ks * 64 + lane) * 8];
    acc = __builtin_amdgcn_mfma_f32_16x16x32_bf16(a, b, acc, 0, 0, 0);
  }
#pragma unroll
  for (int r = 0; r < 4; ++r) {
    int row = row0 + quad * 4 + r;
    if (row < N) {
      if (l16 < 8) a_s[(size_t)row * 8 + l16] = acc[r];
      else         a_d[(size_t)row * 8 + (l16 - 8)] = acc[r];
    }
  }
}

// ---------- CSR fill + per-edge softmax weights (bf16 x8, CSR slot order) ----
// col[pos] = src | (dest&15)<<27  (dest-local id within the 16-dest tile).
// NO global atomics beyond the cursor (round-7 lesson: 8 f32 atomics/edge on
// hot per-dest addresses = 198us of RMW serialization).
__global__ void fill_weight_kernel(const int* __restrict__ ei, int E, int Etot,
                                   const float* __restrict__ a_s,
                                   const float* __restrict__ a_d,
                                   int* __restrict__ cursor,
                                   int* __restrict__ col,
                                   unsigned short* __restrict__ wedge) {
  int e = blockIdx.x * 256 + threadIdx.x;
  if (e >= Etot) return;
  int s, d;
  if (e < E) { s = ei[e]; d = ei[E + e]; } else { s = d = e - E; }
  int pos = atomicAdd(&cursor[d], 1);
  col[pos] = s | ((d & 15) << 27);
  float4 s0 = *(const float4*)(a_s + (size_t)s * 8);
  float4 s1 = *(const float4*)(a_s + (size_t)s * 8 + 4);
  float4 d0 = *(const float4*)(a_d + (size_t)d * 8);
  float4 d1 = *(const float4*)(a_d + (size_t)d * 8 + 4);
  float v, w0, w1, w2, w3, w4, w5, w6, w7;
  v = s0.x + d0.x; v = v > 0.f ? v : NEG * v; w0 = __expf(v);
  v = s0.y + d0.y; v = v > 0.f ? v : NEG * v; w1 = __expf(v);
  v = s0.z + d0.z; v = v > 0.f ? v : NEG * v; w2 = __expf(v);
  v = s0.w + d0.w; v = v > 0.f ? v : NEG * v; w3 = __expf(v);
  v = s1.x + d1.x; v = v > 0.f ? v : NEG * v; w4 = __expf(v);
  v = s1.y + d1.y; v = v > 0.f ? v : NEG * v; w5 = __expf(v);
  v = s1.z + d1.z; v = v > 0.f ? v : NEG * v; w6 = __expf(v);
  v = s1.w + d1.w; v = v > 0.f ? v : NEG * v; w7 = __expf(v);
  uint4 o;
  o.x = pack2(w0, w1); o.y = pack2(w2, w3);
  o.z = pack2(w4, w5); o.w = pack2(w6, w7);
  *(uint4*)(wedge + (size_t)pos * 8) = o;
}

// ---------- MFMA-based x-space aggregation + W1 GEMM -> out1 ----------
// Block = 512 threads (8 waves), TILE = 16 dests, chunks of 32 edge slots:
//   stage XgT[128f][32k] bf16: paired-b32 writes, per-pair XOR swizzle
//   build Wm[8h][16d][32k] bf16 masked weights (dl pre-packed in col bits 27+)
//   wave h: accw[ft] += MFMA(Wm[h], XgT[ft]); accdn += MFMA(Wm[h], ones)
// Denominator = ones-column MFMA (col 0 of accdn) — in-kernel, no atomics.
// LDS: {XgT 8K + Wm 8K} UNION {AggP 34.8K}. launch_bounds(512,6): 3 blocks/CU,
// VGPR budget 85 — no spills (round-6 lesson: (512,8) forced 190MB of scratch).
__global__ __launch_bounds__(512, 6) void aggx_gemm1_kernel(
    const unsigned short* __restrict__ xbf,     // N x 128 bf16
    const unsigned short* __restrict__ W1frag,  // [32][4][64][8] bf16 (natural k)
    const int* __restrict__ rowptr,
    const int* __restrict__ col,                // src | dl<<27
    const unsigned short* __restrict__ wedge,   // Etot x 8 bf16 (CSR order)
    const float* __restrict__ bias_perm,        // 512, PERMUTED
    unsigned short* __restrict__ out1,          // N x 512 bf16 (PERMUTED)
    int N) {
  __shared__ __align__(16) char LB[8 * 16 * 136 * 2];   // 34816 B union
  unsigned short* XgT = (unsigned short*)LB;            // 8 KB (chunk loop)
  unsigned short* Wm  = (unsigned short*)(LB + 8192);   // 8 KB (chunk loop)
  unsigned short* AggP = (unsigned short*)LB;           // 34.8 KB (epilogue)

  int t = threadIdx.x, w = t >> 6, lane = t & 63;
  int q = lane >> 4, n = lane & 15;
  int dbase = blockIdx.x * 16;

  int R0 = rowptr[dbase];
  int R1 = rowptr[min(dbase + 16, N)];
  int nch = (R1 - R0 + 31) >> 5;

  // staging ids: kp = edge-pair (0..15), pp = feature-quad (0..31)
  int kp = t >> 5, pp = t & 31;
  int skey = ((pp >> 1) & 7) << 4;       // = ((f>>3)&7)<<4 for f = 4*pp+df
  // wmat ids
  int dw = t >> 5, kw = t & 31;

  // ones B-fragment: B[k][n] = (n==0) ? 1.0bf16 : 0
  short8 onesf = {};
  if (n == 0) {
#pragma unroll
    for (int j = 0; j < 8; ++j) onesf[j] = (short)0x3F80;
  }

  floatx4 accw[8] = {};
  floatx4 accdn = {};

  for (int c = 0; c < nch; ++c) {
    int ebase = R0 + c * 32;
    __syncthreads();                       // prior chunk's MFMA reads done

    // ---- stage XgT: element (f,k) at byte (64f + 2k) ^ ((f>>3&7)<<4).
    // Thread handles edges 2kp, 2kp+1 x features 4pp..4pp+3; the two k
    // elements of one f share a dword -> 4 b32 writes (key bits 4-6 never
    // touch bits 0-1, so pairs stay adjacent after XOR).
    {
      int e0 = ebase + 2 * kp;
      int ec0 = (e0 < R1) ? e0 : (R1 - 1);
      int ec1 = (e0 + 1 < R1) ? (e0 + 1) : (R1 - 1);
      int s0 = col[ec0] & SMASK;
      int s1 = col[ec1] & SMASK;
      uint2 xa = *(const uint2*)(xbf + (size_t)s0 * 128 + pp * 4);
      uint2 xb = *(const uint2*)(xbf + (size_t)s1 * 128 + pp * 4);
      int base = 256 * pp + 4 * kp;        // byte addr of (f=4pp, k=2kp)
      unsigned w0 = (xa.x & 0xffffu) | (xb.x << 16);
      unsigned w1 = (xa.x >> 16) | (xb.x & 0xffff0000u);
      unsigned w2 = (xa.y & 0xffffu) | (xb.y << 16);
      unsigned w3 = (xa.y >> 16) | (xb.y & 0xffff0000u);
      *(unsigned*)((char*)XgT + ((base)       ^ skey)) = w0;
      *(unsigned*)((char*)XgT + ((base + 64)  ^ skey)) = w1;
      *(unsigned*)((char*)XgT + ((base + 128) ^ skey)) = w2;
      *(unsigned*)((char*)XgT + ((base + 192) ^ skey)) = w3;
    }
    // ---- build Wm: dl pre-packed in col, weights already bf16 ----
    {
      int ew = ebase + kw;
      bool evw = ew < R1;
      int ewc = evw ? ew : (R1 - 1);
      int cv = col[ewc];
      int dl = (cv >> 27) & 15;
      uint4 wv = *(const uint4*)(wedge + (size_t)ewc * 8);
      bool mine = evw && (dl == dw);
      unsigned short* wmp = Wm + dw * 32 + kw;
      wmp[0]    = mine ? (unsigned short)(wv.x & 0xffff) : 0;
      wmp[512]  = mine ? (unsigned short)(wv.x >> 16)    : 0;
      wmp[1024] = mine ? (unsigned short)(wv.y & 0xffff) : 0;
      wmp[1536] = mine ? (unsigned short)(wv.y >> 16)    : 0;
      wmp[2048] = mine ? (unsigned short)(wv.z & 0xffff) : 0;
      wmp[2560] = mine ? (unsigned short)(wv.z >> 16)    : 0;
      wmp[3072] = mine ? (unsigned short)(wv.w & 0xffff) : 0;
      wmp[3584] = mine ? (unsigned short)(wv.w >> 16)    : 0;
    }
    __syncthreads();

    // ---- MFMA: wave w = head w ----
    short8 af = *(const short8*)(Wm + w * 512 + n * 32 + 8 * q);
    accdn = __builtin_amdgcn_mfma_f32_16x16x32_bf16(af, onesf, accdn, 0, 0, 0);
#pragma unroll
    for (int ft = 0; ft < 8; ++ft) {
      int bb = (ft * 16 + n) * 64 + 16 * q;
      bb ^= ((bb >> 9) & 7) << 4;
      short8 bfr = *(const short8*)((const char*)XgT + bb);
      accw[ft] = __builtin_amdgcn_mfma_f32_16x16x32_bf16(af, bfr, accw[ft], 0, 0, 0);
    }
  }

  __syncthreads();                         // last MFMA reads done before AggP

  // ---- epilogue: normalize (denominator from accdn col 0), write AggP ----
  {
    float dnv[4];
#pragma unroll
    for (int r = 0; r < 4; ++r) {
      float dr = __shfl(accdn[r], lane & 48);      // broadcast col-0 lane of quad
      dnv[r] = rcp_nr(dr + 1e-16f);
    }
#pragma unroll
    for (int ft = 0; ft < 8; ++ft)
#pragma unroll
      for (int r = 0; r < 4; ++r)
        AggP[w * 2176 + (4 * q + r) * 136 + ft * 16 + n] =
            f2bbits(accw[ft][r] * dnv[r]);
  }
  __syncthreads();

  // ---- phase 3: per-head W1 GEMM, bias + ELU, permuted store ----
  {
    int hp = w >> 1, qq = w & 1;
    floatx4 acc2[4] = {};
    const unsigned short* Bp = W1frag + (size_t)hp * 16384;
#pragma unroll
    for (int ks = 0; ks < 4; ++ks) {
      short8 a2 = *(const short8*)&AggP[w * 2176 + n * 136 + ks * 32 + q * 8];
#pragma unroll
      for (int j = 0; j < 4; ++j) {
        int nt = qq * 4 + j;
        short8 b2 = *(const short8*)&Bp[((nt * 4 + ks) * 64 + lane) * 8];
        acc2[j] = __builtin_amdgcn_mfma_f32_16x16x32_bf16(a2, b2, acc2[j], 0, 0, 0);
      }
    }
    float4 bq = *(const float4*)&bias_perm[hp * 128 + n * 8 + qq * 4];
#pragma unroll
    for (int r = 0; r < 4; ++r) {
      int row = dbase + 4 * q + r;
      if (row < N) {
        uint2 o;
        o.x = pack2(elu1(acc2[0][r] + bq.x), elu1(acc2[1][r] + bq.y));
        o.y = pack2(elu1(acc2[2][r] + bq.z), elu1(acc2[3][r] + bq.w));
        *(uint2*)&out1[(size_t)row * 512 + hp * 128 + n * 8 + qq * 4] = o;
      }
    }
  }
}

// ---------- layer 2: MFMA bf16 GEMM (k-dim permuted to match out1bf) ----------
__global__ __launch_bounds__(256) void gemm2_mfma_kernel(
    const unsigned short* __restrict__ x2bf,    // N x 512 bf16 (PERMUTED k)
    const unsigned short* __restrict__ W2frag,  // [16ks][4nt][64][8] bf16 (perm k)
    const float* __restrict__ att_src,          // 64
    const float* __restrict__ att_dst,
    unsigned short* __restrict__ h2,            // N x 64 bf16 (natural)
    float* __restrict__ a_s, float* __restrict__ a_d,  // N
    int N) {
  int t = threadIdx.x;
  int w = t >> 6, lane = t & 63;
  int quad = lane >> 4, l16 = lane & 15;
  int rowbase = blockIdx.x * 64 + w * 16;

  floatx4 acc[4] = {};
  int r0 = rowbase + l16; if (r0 >= N) r0 = N - 1;
  const unsigned short* p0 = x2bf + (size_t)r0 * 512 + quad * 8;
#pragma unroll
  for (int ks = 0; ks < 16; ++ks) {
    short8 a0 = *(const short8*)(p0 + ks * 32);
#pragma unroll
    for (int nt = 0; nt < 4; ++nt) {
      short8 b = *(const short8*)&W2frag[((ks * 4 + nt) * 64 + lane) * 8];
      acc[nt] = __builtin_amdgcn_mfma_f32_16x16x32_bf16(a0, b, acc[nt], 0, 0, 0);
    }
  }

  float asw[4], adw[4];
#pragma unroll
  for (int nt = 0; nt < 4; ++nt) {
    asw[nt] = att_src[nt * 16 + l16];
    adw[nt] = att_dst[nt * 16 + l16];
  }
  float ps[4] = {}, pd[4] = {};
#pragma unroll
  for (int nt = 0; nt < 4; ++nt)
#pragma unroll
    for (int r = 0; r < 4; ++r) {
      float v = acc[nt][r];
      int row = rowbase + quad * 4 + r;
      if (row < N) h2[(size_t)row * 64 + nt * 16 + l16] = f2bbits(v);
      ps[r] += v * asw[nt];
      pd[r] += v * adw[nt];
    }
#pragma unroll
  for (int r = 0; r < 4; ++r) {
    float p = ps[r], q = pd[r];
#pragma unroll
    for (int off = 1; off < 16; off <<= 1) {
      p += __shfl_xor(p, off);
      q += __shfl_xor(q, off);
    }
    int row = rowbase + quad * 4 + r;
    if (l16 == 0 && row < N) {
      a_s[row] = p;
      a_d[row] = q;
    }
  }
}

// H=1, quarter-wave edge grouping (h2 natural layout).
__global__ void gat_agg1_kernel(const int* __restrict__ rowptr,
                                const int* __restrict__ col,
                                const float* __restrict__ a_s,
                                const float* __restrict__ a_d,
                                const unsigned short* __restrict__ hfeat,
                                const float* __restrict__ bias,
                                unsigned short* __restrict__ out, int N) {
  int wave = threadIdx.x >> 6, lane = threadIdx.x & 63;
  int d = blockIdx.x * 4 + wave;
  if (d >= N) return;
  int beg = rowptr[d], end = rowptr[d + 1];
  int qg = lane >> 4, l16 = lane & 15;
  float adv = a_d[d];
  const uint2* hfu = (const uint2*)hfeat;
  float acc[4] = {};
  float wsum = 0.f;
#pragma unroll 2
  for (int i = beg + qg; i < end; i += 4) {
    int s = col[i] & SMASK;
    float v = a_s[s] + adv;
    v = v > 0.f ? v : NEG * v;
    float wv = __expf(v);
    wsum += wv;
    uint2 u = hfu[(size_t)s * 16 + l16];
    acc[0] += wv * blo(u.x); acc[1] += wv * bhi(u.x);
    acc[2] += wv * blo(u.y); acc[3] += wv * bhi(u.y);
  }
#pragma unroll
  for (int off = 16; off <= 32; off <<= 1) {
#pragma unroll
    for (int j = 0; j < 4; ++j) acc[j] += __shfl_xor(acc[j], off);
    wsum += __shfl_xor(wsum, off);
  }
  float winv = 1.f / (wsum + 1e-16f);
  float4 bb = ((const float4*)bias)[l16];
  float r0 = elu1(acc[0] * winv + bb.x), r1 = elu1(acc[1] * winv + bb.y);
  float r2 = elu1(acc[2] * winv + bb.z), r3 = elu1(acc[3] * winv + bb.w);
  if (qg == 0) {
    uint2 o; o.x = pack2(r0, r1); o.y = pack2(r2, r3);
    ((uint2*)out)[(size_t)d * 16 + l16] = o;
  }
}

// ---------- pooling: 16 nodes per wave ----------
__global__ void pool_kernel(const unsigned short* __restrict__ out2,
                            const int* __restrict__ batch,
                            float* __restrict__ pooled, int N) {
  int wave = threadIdx.x >> 6, lane = threadIdx.x & 63;
  int seg = blockIdx.x * 4 + wave;
  int start = seg * 16;
  if (start >= N) return;
  int end = min(start + 16, N);
  int cur = batch[start];
  float acc = 0.f;
  for (int n = start; n < end; ++n) {
    int bn = batch[n];
    if (bn != cur) {
      unsafeAtomicAdd(&pooled[cur * 64 + lane], acc);
      acc = 0.f; cur = bn;
    }
    acc += bu(out2[(size_t)n * 64 + lane]);
  }
  unsafeAtomicAdd(&pooled[cur * 64 + lane], acc);
}

// ---------- MLP head + log_softmax: one block (one wave) per graph ----------
__global__ void head_kernel(const float* __restrict__ pooled,
                            const float* __restrict__ lin1_w,
                            const float* __restrict__ lin1_b,
                            const float* __restrict__ lin2_w,
                            const float* __restrict__ lin2_b,
                            const void* __restrict__ x_raw,
                            void* __restrict__ outv) {
  __shared__ float P[C];
  __shared__ float Zs[C];
  __shared__ float Ls[K];
  __shared__ float lse_s;
  __shared__ int fl;
  int isbf = detect_dev(x_raw, &fl);
  int g = blockIdx.x, t = threadIdx.x;   // 64 threads
  P[t] = pooled[g * C + t];
  __syncthreads();
  float acc = lin1_b[t];
  for (int k = 0; k < C; ++k) acc += P[k] * lin1_w[k * C + t];
  Zs[t] = elu1(acc);
  __syncthreads();
  if (t < K) {
    float a = lin2_b[t];
    for (int k = 0; k < C; ++k) a += Zs[k] * lin2_w[k * K + t];
    Ls[t] = a;
  }
  __syncthreads();
  if (t == 0) {
    float mx = -1e30f;
    for (int c = 0; c < K; ++c) mx = fmaxf(mx, Ls[c]);
    float s = 0.f;
    for (int c = 0; c < K; ++c) s += __expf(Ls[c] - mx);
    lse_s = mx + __logf(s);
  }
  __syncthreads();
  if (t < K) {
    float val = Ls[t] - lse_s;
    if (isbf) ((__hip_bfloat16*)outv)[g * K + t] = __float2bfloat16(val);
    else      ((float*)outv)[g * K + t] = val;
  }
}

extern "C" void kernel_launch(void* const* d_in, const int* in_sizes, int n_in,
                              void* d_out, int out_size, void* d_ws, size_t ws_size,
                              hipStream_t stream) {
  const void* x_raw = d_in[0];
  const int*  ei    = (const int*)d_in[1];
  const int*  batch = (const int*)d_in[2];

  const int N    = in_sizes[2];
  const int E    = in_sizes[1] / 2;
  const int Etot = E + N;
  const int nb   = (N + 255) / 256;

  float* ws   = (float*)d_ws;
  size_t off  = 0;

  float* wts = ws + off; off += 6544;
  float* b1w  = wts + 1024;
  float* as2w = wts + 1536;
  float* ad2w = wts + 1600;
  float* b2w  = wts + 1664;
  float* l1w  = wts + 1728;
  float* l1b  = wts + 5824;
  float* l2w  = wts + 5888;
  float* l2b  = wts + 6528;

  unsigned short* xbf    = (unsigned short*)(ws + off); off += (size_t)N * 64;
  unsigned short* w1frag = (unsigned short*)(ws + off); off += 32768;
  unsigned short* w2frag = (unsigned short*)(ws + off); off += 16384;
  unsigned short* vfrag  = (unsigned short*)(ws + off); off += 1024;
  unsigned short* wedge  = (unsigned short*)(ws + off); off += (size_t)Etot * 4;
  unsigned short* out1bf = (unsigned short*)(ws + off); off += (size_t)N * 256;
  unsigned short* h2bf   = (unsigned short*)(ws + off); off += (size_t)N * 32;
  unsigned short* out2bf = (unsigned short*)(ws + off); off += (size_t)N * 32;
  float* as1  = ws + off; off += (size_t)N * H1;
  float* ad1  = ws + off; off += (size_t)N * H1;
  float* as2  = ws + off; off += (size_t)N;
  float* ad2  = ws + off; off += (size_t)N;
  float* pooled = ws + off; off += (size_t)B * C;

  int* ibase  = (int*)(ws + off);
  int* deg    = ibase;                 ibase += N;
  int* cursor = ibase;                 ibase += N;
  int* rowptr = ibase;                 ibase += N + 1;
  int* locals = ibase;                 ibase += N;
  int* bsum   = ibase;                 ibase += 256;
  int* col    = ibase;                 ibase += Etot;

  // ---- prep ----
  fused_prep_kernel<<<1024, 256, 0, stream>>>(
      x_raw, d_in[3], d_in[4], d_in[5], d_in[6], d_in[7], d_in[8], d_in[9],
      d_in[10], d_in[11], d_in[12], d_in[13], d_in[14],
      xbf, w1frag, w2frag, vfrag, wts, deg, pooled, in_sizes[0], N);

  // ---- CSR: deg + scans ----
  deg_count_kernel<<<(Etot + 255) / 256, 256, 0, stream>>>(ei, E, Etot, deg);
  scan_block_kernel<<<nb, 256, 0, stream>>>(deg, locals, bsum, N);
  scan_finish_kernel<<<nb, 256, 0, stream>>>(locals, bsum, nb, rowptr, cursor, N, Etot);

  // ---- layer-1 attention scalars via factored V (tiny MFMA GEMM) ----
  att_scalars_kernel<<<(N + 63) / 64, 256, 0, stream>>>(xbf, vfrag, as1, ad1, N);

  // ---- CSR fill + per-edge softmax weights (bf16) ----
  fill_weight_kernel<<<(Etot + 255) / 256, 256, 0, stream>>>(
      ei, E, Etot, as1, ad1, cursor, col, wedge);

  // ---- MFMA x-space aggregation + W1 GEMM -> out1 ----
  aggx_gemm1_kernel<<<(N + 15) / 16, 512, 0, stream>>>(
      xbf, w1frag, rowptr, col, wedge, b1w, out1bf, N);

  // ---- layer 2 ----
  gemm2_mfma_kernel<<<(N + 63) / 64, 256, 0, stream>>>(out1bf, w2frag, as2w, ad2w,
                                                       h2bf, as2, ad2, N);
  gat_agg1_kernel<<<(N + 3) / 4, 256, 0, stream>>>(rowptr, col, as2, ad2, h2bf, b2w, out2bf, N);

  // ---- pool + head ----
  pool_kernel<<<(N + 63) / 64, 256, 0, stream>>>(out2bf, batch, pooled, N);
  head_kernel<<<B, 64, 0, stream>>>(pooled, l1w, l1b, l2w, l2b, x_raw, (void*)d_out);
}

// Round 9
// 285.585 us; speedup vs baseline: 1.6173x; 1.0363x over previous
//
#include <hip/hip_runtime.h>
#include <hip/hip_bf16.h>

#define DEV static __device__ __forceinline__

constexpr int F1 = 128;   // input features
constexpr int H1 = 8;     // heads layer1
constexpr int C  = 64;    // channels per head
constexpr int B  = 64;    // graphs
constexpr int K  = 10;    // classes
constexpr float NEG = 0.2f;
constexpr unsigned SMASK = 0x07FFFFFFu;   // col[] low bits = src id; bits 27-30 = dest&15

typedef __attribute__((ext_vector_type(8))) short short8;
typedef __attribute__((ext_vector_type(4))) float floatx4;

DEV float b2f(__hip_bfloat16 x) { return __bfloat162float(x); }
DEV float elu1(float v) { return v > 0.f ? v : (__expf(v) - 1.f); }
DEV unsigned short f2bbits(float f) {
  __hip_bfloat16 b = __float2bfloat16(f);
  return *(unsigned short*)&b;
}
DEV float blo(unsigned u) { return __uint_as_float(u << 16); }
DEV float bhi(unsigned u) { return __uint_as_float(u & 0xffff0000u); }
DEV float bu(unsigned short u) { return __uint_as_float(((unsigned)u) << 16); }
DEV unsigned pack2(float lo, float hi) {
  return (unsigned)f2bbits(lo) | ((unsigned)f2bbits(hi) << 16);
}
// 1/x via v_rcp_f32 + one Newton step
DEV float rcp_nr(float x) {
  float r = __builtin_amdgcn_rcpf(x);
  return r * (2.f - x * r);
}

// out1 PERMUTED layout: position p = hp*128 + l16*8 + nt  <->  natural channel
// c = hp*128 + nt*16 + l16. W2frag k-rows and b1 permuted to match.
// W1frag k is NATURAL.

// Self-detection: thread 0 samples 128 even-index bf16 reinterps of x.
DEV int detect_dev(const void* xraw, int* lds) {
  if (threadIdx.x == 0) {
    const __hip_bfloat16* xb = (const __hip_bfloat16*)xraw;
    int bad = 0;
    for (int i = 0; i < 128; ++i) {
      float v = b2f(xb[2 * i]);
      if (!(fabsf(v) < 1e4f)) bad++;
    }
    *lds = (bad < 13) ? 1 : 0;     // 1 = bf16, 0 = f32
  }
  __syncthreads();
  return *lds;
}

#define CVT(p, i) (isbf ? b2f(((const __hip_bfloat16*)(p))[i]) : ((const float*)(p))[i])

// ---------- fused prep ----------
__global__ void fused_prep_kernel(const void* x_raw, const void* w1raw,
                                  const void* as1r, const void* ad1r, const void* b1r,
                                  const void* w2raw,
                                  const void* as2r, const void* ad2r, const void* b2r,
                                  const void* l1wr, const void* l1br,
                                  const void* l2wr, const void* l2br,
                                  unsigned short* __restrict__ xbf,
                                  unsigned short* __restrict__ w1frag,
                                  unsigned short* __restrict__ w2frag,
                                  unsigned short* __restrict__ vfrag,
                                  float* __restrict__ wts,
                                  int* __restrict__ deg,
                                  float* __restrict__ pooled,
                                  int nX, int N) {
  __shared__ int fl;
  int isbf = detect_dev(x_raw, &fl);
  int gid = blockIdx.x * 256 + threadIdx.x;
  int stride = gridDim.x * 256;

  if (isbf) {
    const unsigned short* src = (const unsigned short*)x_raw;
    for (int i = gid; i < nX; i += stride) xbf[i] = src[i];
  } else {
    const float* src = (const float*)x_raw;
    for (int i = gid; i < nX; i += stride) xbf[i] = f2bbits(src[i]);
  }
  // b1 stored PERMUTED: wts[1024 + p] = b1[c_nat(p)]
  for (int i = gid; i < 512;  i += stride) {
    int hp = i >> 7, l16 = (i >> 3) & 15, nt = i & 7;
    int c = hp * 128 + nt * 16 + l16;
    wts[1024 + i] = CVT(b1r, c);
  }
  for (int i = gid; i < 64;   i += stride) wts[1536 + i] = CVT(as2r, i);
  for (int i = gid; i < 64;   i += stride) wts[1600 + i] = CVT(ad2r, i);
  for (int i = gid; i < 64;   i += stride) wts[1664 + i] = CVT(b2r, i);
  for (int i = gid; i < 4096; i += stride) wts[1728 + i] = CVT(l1wr, i);
  for (int i = gid; i < 64;   i += stride) wts[5824 + i] = CVT(l1br, i);
  for (int i = gid; i < 640;  i += stride) wts[5888 + i] = CVT(l2wr, i);
  for (int i = gid; i < 10;   i += stride) wts[6528 + i] = CVT(l2br, i);
  // W1frag NATURAL k
  for (int t = gid; t < 8192; t += stride) {
    int lane = t & 63, ks = (t >> 6) & 3, nt = t >> 8;
    for (int j = 0; j < 8; ++j) {
      int k = ks * 32 + (lane >> 4) * 8 + j;
      int n = nt * 16 + (lane & 15);
      w1frag[t * 8 + j] = f2bbits(CVT(w1raw, k * 512 + n));
    }
  }
  // W2frag with PERMUTED k: k index in fragment = position p; fetch W2[c_nat(p)]
  for (int t = gid; t < 4096; t += stride) {
    int lane = t & 63, nt = (t >> 6) & 3, ks = t >> 8;
    for (int j = 0; j < 8; ++j) {
      int p = ks * 32 + (lane >> 4) * 8 + j;          // permuted position
      int hp = p >> 7, pl16 = (p >> 3) & 15, pnt = p & 7;
      int k = hp * 128 + pnt * 16 + pl16;             // natural channel
      int n = nt * 16 + (lane & 15);
      w2frag[t * 8 + j] = f2bbits(CVT(w2raw, k * 64 + n));
    }
  }
  // Vfrag: B-fragment of V[128 x 16], V[:,n<8] = W1 head-n col @ att_src[n],
  // V[:,n>=8] = same with att_dst. a_s/a_d = x @ V.
  for (int t = gid; t < 2048; t += stride) {
    int j = t & 7, lane = (t >> 3) & 63, ks = t >> 9;
    int k = ks * 32 + (lane >> 4) * 8 + j;
    int n = lane & 15;
    int hh = (n < 8) ? n : (n - 8);
    float s = 0.f;
    if (n < 8) {
      for (int c = 0; c < 64; ++c)
        s += CVT(w1raw, k * 512 + hh * 64 + c) * CVT(as1r, hh * 64 + c);
    } else {
      for (int c = 0; c < 64; ++c)
        s += CVT(w1raw, k * 512 + hh * 64 + c) * CVT(ad1r, hh * 64 + c);
    }
    vfrag[(ks * 64 + lane) * 8 + j] = f2bbits(s);
  }
  for (int i = gid; i < N; i += stride) deg[i] = 0;
  for (int i = gid; i < B * C; i += stride) pooled[i] = 0.f;
}

// ---------- degree count ----------
__global__ void deg_count_kernel(const int* __restrict__ ei, int E, int Etot,
                                 int* __restrict__ deg) {
  int e = blockIdx.x * blockDim.x + threadIdx.x;
  if (e >= Etot) return;
  int d = (e < E) ? ei[E + e] : e - E;
  atomicAdd(&deg[d], 1);
}

// ---------- CSR scans ----------
__global__ void scan_block_kernel(const int* __restrict__ deg,
                                  int* __restrict__ local,
                                  int* __restrict__ bsum, int N) {
  __shared__ int tmp[256];
  int t = threadIdx.x;
  int i = blockIdx.x * 256 + t;
  int v = (i < N) ? deg[i] : 0;
  tmp[t] = v;
  __syncthreads();
  for (int off = 1; off < 256; off <<= 1) {
    int u = (t >= off) ? tmp[t - off] : 0;
    __syncthreads();
    tmp[t] += u;
    __syncthreads();
  }
  if (i < N) local[i] = tmp[t] - v;
  if (t == 255) bsum[blockIdx.x] = tmp[255];
}

__global__ void scan_finish_kernel(const int* __restrict__ local,
                                   const int* __restrict__ bsum, int nb,
                                   int* __restrict__ rowptr,
                                   int* __restrict__ cursor, int N, int Etot) {
  __shared__ int tmp[256];
  __shared__ int offs;
  int t = threadIdx.x;
  int v0 = (t < nb) ? bsum[t] : 0;
  tmp[t] = v0;
  __syncthreads();
  for (int off = 1; off < 256; off <<= 1) {
    int u = (t >= off) ? tmp[t - off] : 0;
    __syncthreads();
    tmp[t] += u;
    __syncthreads();
  }
  if (t == (int)blockIdx.x) offs = tmp[t] - v0;
  __syncthreads();
  int i = blockIdx.x * 256 + t;
  if (i < N) {
    int r = local[i] + offs;
    rowptr[i] = r;
    cursor[i] = r;
  }
  if (i == 0) rowptr[N] = Etot;
}

// ---------- attention scalars: a_s/a_d = x @ V  (4 MFMA per 16 rows) ----------
__global__ __launch_bounds__(256) void att_scalars_kernel(
    const unsigned short* __restrict__ xbf,     // N x 128 bf16
    const unsigned short* __restrict__ vfrag,   // [4ks][64][8] bf16
    float* __restrict__ a_s, float* __restrict__ a_d,   // N x 8
    int N) {
  int t = threadIdx.x, w = t >> 6, lane = t & 63;
  int quad = lane >> 4, l16 = lane & 15;
  int row0 = blockIdx.x * 64 + w * 16;

  floatx4 acc = {};
  int rl = row0 + l16; if (rl >= N) rl = N - 1;
  const unsigned short* xp = xbf + (size_t)rl * 128 + quad * 8;
#pragma unroll
  for (int ks = 0; ks < 4; ++ks) {
    short8 a = *(const short8*)(xp + ks * 32);
    short8 b = *(const short8*)&vfrag[(ks * 64 + lane) * 8];
    acc = __builtin_amdgcn_mfma_f32_16x16x32_bf16(a, b, acc, 0, 0, 0);
  }
#pragma unroll
  for (int r = 0; r < 4; ++r) {
    int row = row0 + quad * 4 + r;
    if (row < N) {
      if (l16 < 8) a_s[(size_t)row * 8 + l16] = acc[r];
      else         a_d[(size_t)row * 8 + (l16 - 8)] = acc[r];
    }
  }
}

// ---------- CSR fill + per-edge softmax weights (bf16 x8, CSR slot order) ----
// col[pos] = src | (dest&15)<<27  (dest-local id within the 16-dest tile).
// NO global atomics beyond the cursor (round-7 lesson: 8 f32 atomics/edge on
// hot per-dest addresses = 198us of RMW serialization).
__global__ void fill_weight_kernel(const int* __restrict__ ei, int E, int Etot,
                                   const float* __restrict__ a_s,
                                   const float* __restrict__ a_d,
                                   int* __restrict__ cursor,
                                   int* __restrict__ col,
                                   unsigned short* __restrict__ wedge) {
  int e = blockIdx.x * 256 + threadIdx.x;
  if (e >= Etot) return;
  int s, d;
  if (e < E) { s = ei[e]; d = ei[E + e]; } else { s = d = e - E; }
  int pos = atomicAdd(&cursor[d], 1);
  col[pos] = s | ((d & 15) << 27);
  float4 s0 = *(const float4*)(a_s + (size_t)s * 8);
  float4 s1 = *(const float4*)(a_s + (size_t)s * 8 + 4);
  float4 d0 = *(const float4*)(a_d + (size_t)d * 8);
  float4 d1 = *(const float4*)(a_d + (size_t)d * 8 + 4);
  float v, w0, w1, w2, w3, w4, w5, w6, w7;
  v = s0.x + d0.x; v = v > 0.f ? v : NEG * v; w0 = __expf(v);
  v = s0.y + d0.y; v = v > 0.f ? v : NEG * v; w1 = __expf(v);
  v = s0.z + d0.z; v = v > 0.f ? v : NEG * v; w2 = __expf(v);
  v = s0.w + d0.w; v = v > 0.f ? v : NEG * v; w3 = __expf(v);
  v = s1.x + d1.x; v = v > 0.f ? v : NEG * v; w4 = __expf(v);
  v = s1.y + d1.y; v = v > 0.f ? v : NEG * v; w5 = __expf(v);
  v = s1.z + d1.z; v = v > 0.f ? v : NEG * v; w6 = __expf(v);
  v = s1.w + d1.w; v = v > 0.f ? v : NEG * v; w7 = __expf(v);
  uint4 o;
  o.x = pack2(w0, w1); o.y = pack2(w2, w3);
  o.z = pack2(w4, w5); o.w = pack2(w6, w7);
  *(uint4*)(wedge + (size_t)pos * 8) = o;
}

// ---------- MFMA-based x-space aggregation + W1 GEMM -> out1 ----------
// Block = 512 threads (8 waves), TILE = 16 dests, chunks of 32 edge slots.
// PIPELINED (T14): iteration c writes prefetched regs -> buf[c&1], issues
// chunk c+1 loads (col -> x -> wedge) into regs, ONE barrier, MFMA buf[c&1].
// Safety: a wave writing buf[c&1] has passed barrier(c-1); every wave reaches
// barrier(c-1) only after its MFMA(c-2), which was the last reader of buf[c&1].
// Swizzle key = f bits 2-4: element (f,k) at byte (64f+2k) ^ ((f>>2)&7)<<4.
// Write side: f>>2 == pp exactly (df<4) -> skey = (pp&7)<<4, const per thread.
// LDS: 2 x {XgT 8K + Wm 8K} dbuf UNION AggP 34.8K -> 34816 B total.
__global__ __launch_bounds__(512, 6) void aggx_gemm1_kernel(
    const unsigned short* __restrict__ xbf,     // N x 128 bf16
    const unsigned short* __restrict__ W1frag,  // [32][4][64][8] bf16 (natural k)
    const int* __restrict__ rowptr,
    const int* __restrict__ col,                // src | dl<<27
    const unsigned short* __restrict__ wedge,   // Etot x 8 bf16 (CSR order)
    const float* __restrict__ bias_perm,        // 512, PERMUTED
    unsigned short* __restrict__ out1,          // N x 512 bf16 (PERMUTED)
    int N) {
  __shared__ __align__(16) char LB[8 * 16 * 136 * 2];   // 34816 B union
  unsigned short* AggP = (unsigned short*)LB;           // 34.8 KB (epilogue)

  int t = threadIdx.x, w = t >> 6, lane = t & 63;
  int q = lane >> 4, n = lane & 15;
  int dbase = blockIdx.x * 16;

  int R0 = rowptr[dbase];
  int R1 = rowptr[min(dbase + 16, N)];
  int nch = (R1 - R0 + 31) >> 5;

  // staging ids: kp = edge-pair (0..15), pp = feature-quad (0..31)
  int kp = t >> 5, pp = t & 31;
  int skey = (pp & 7) << 4;              // = ((f>>2)&7)<<4 for f = 4*pp+df
  // wmat ids
  int dw = t >> 5, kw = t & 31;

  // ones B-fragment: B[k][n] = (n==0) ? 1.0bf16 : 0
  short8 onesf = {};
  if (n == 0) {
#pragma unroll
    for (int j = 0; j < 8; ++j) onesf[j] = (short)0x3F80;
  }

  floatx4 accw[8] = {};
  floatx4 accdn = {};

  // prefetched chunk data
  uint2 pxa, pxb;
  uint4 pwv;
  int pcv;
  {
    int e0 = R0 + 2 * kp;
    int ec0 = min(e0, R1 - 1), ec1 = min(e0 + 1, R1 - 1);
    int s0 = col[ec0] & SMASK;
    int s1 = col[ec1] & SMASK;
    pxa = *(const uint2*)(xbf + (size_t)s0 * 128 + pp * 4);
    pxb = *(const uint2*)(xbf + (size_t)s1 * 128 + pp * 4);
    int ew = min(R0 + kw, R1 - 1);
    pcv = col[ew];
    pwv = *(const uint4*)(wedge + (size_t)ew * 8);
  }

  for (int c = 0; c < nch; ++c) {
    char* Lb = LB + (c & 1) * 16384;
    unsigned short* XgTc = (unsigned short*)Lb;
    unsigned short* Wmc  = (unsigned short*)(Lb + 8192);

    // ---- phase A: write prefetched chunk c into buf[c&1] ----
    {
      int base = 256 * pp + 4 * kp;
      unsigned w0 = (pxa.x & 0xffffu) | (pxb.x << 16);
      unsigned w1 = (pxa.x >> 16) | (pxb.x & 0xffff0000u);
      unsigned w2 = (pxa.y & 0xffffu) | (pxb.y << 16);
      unsigned w3 = (pxa.y >> 16) | (pxb.y & 0xffff0000u);
      *(unsigned*)(Lb + ((base)       ^ skey)) = w0;
      *(unsigned*)(Lb + ((base + 64)  ^ skey)) = w1;
      *(unsigned*)(Lb + ((base + 128) ^ skey)) = w2;
      *(unsigned*)(Lb + ((base + 192) ^ skey)) = w3;

      int ew = R0 + c * 32 + kw;
      int dl = (pcv >> 27) & 15;
      bool mine = (ew < R1) && (dl == dw);
      unsigned short* wmp = Wmc + dw * 32 + kw;
      wmp[0]    = mine ? (unsigned short)(pwv.x & 0xffff) : 0;
      wmp[512]  = mine ? (unsigned short)(pwv.x >> 16)    : 0;
      wmp[1024] = mine ? (unsigned short)(pwv.y & 0xffff) : 0;
      wmp[1536] = mine ? (unsigned short)(pwv.y >> 16)    : 0;
      wmp[2048] = mine ? (unsigned short)(pwv.z & 0xffff) : 0;
      wmp[2560] = mine ? (unsigned short)(pwv.z >> 16)    : 0;
      wmp[3072] = mine ? (unsigned short)(pwv.w & 0xffff) : 0;
      wmp[3584] = mine ? (unsigned short)(pwv.w >> 16)    : 0;
    }
    // ---- phase B: issue chunk c+1 loads (latency hides under MFMA) ----
    if (c + 1 < nch) {
      int ebase = R0 + (c + 1) * 32;
      int e0 = ebase + 2 * kp;
      int ec0 = min(e0, R1 - 1), ec1 = min(e0 + 1, R1 - 1);
      int s0 = col[ec0] & SMASK;
      int s1 = col[ec1] & SMASK;
      pxa = *(const uint2*)(xbf + (size_t)s0 * 128 + pp * 4);
      pxb = *(const uint2*)(xbf + (size_t)s1 * 128 + pp * 4);
      int ew = min(ebase + kw, R1 - 1);
      pcv = col[ew];
      pwv = *(const uint4*)(wedge + (size_t)ew * 8);
    }
    __syncthreads();

    // ---- phase C: MFMA from buf[c&1]; wave w = head w ----
    short8 af = *(const short8*)(Wmc + w * 512 + n * 32 + 8 * q);
    accdn = __builtin_amdgcn_mfma_f32_16x16x32_bf16(af, onesf, accdn, 0, 0, 0);
#pragma unroll
    for (int ft = 0; ft < 8; ++ft) {
      int f = ft * 16 + n;
      int bb = f * 64 + 16 * q;
      bb ^= ((f >> 2) & 7) << 4;
      short8 bfr = *(const short8*)((const char*)XgTc + bb);
      accw[ft] = __builtin_amdgcn_mfma_f32_16x16x32_bf16(af, bfr, accw[ft], 0, 0, 0);
    }
  }

  __syncthreads();                         // last MFMA reads done before AggP

  // ---- epilogue: normalize (denominator from accdn col 0), write AggP ----
  {
    float dnv[4];
#pragma unroll
    for (int r = 0; r < 4; ++r) {
      float dr = __shfl(accdn[r], lane & 48);      // broadcast col-0 lane of quad
      dnv[r] = rcp_nr(dr + 1e-16f);
    }
#pragma unroll
    for (int ft = 0; ft < 8; ++ft)
#pragma unroll
      for (int r = 0; r < 4; ++r)
        AggP[w * 2176 + (4 * q + r) * 136 + ft * 16 + n] =
            f2bbits(accw[ft][r] * dnv[r]);
  }
  __syncthreads();

  // ---- phase 3: per-head W1 GEMM, bias + ELU, permuted store ----
  {
    int hp = w >> 1, qq = w & 1;
    floatx4 acc2[4] = {};
    const unsigned short* Bp = W1frag + (size_t)hp * 16384;
#pragma unroll
    for (int ks = 0; ks < 4; ++ks) {
      short8 a2 = *(const short8*)&AggP[w * 2176 + n * 136 + ks * 32 + q * 8];
#pragma unroll
      for (int j = 0; j < 4; ++j) {
        int nt = qq * 4 + j;
        short8 b2 = *(const short8*)&Bp[((nt * 4 + ks) * 64 + lane) * 8];
        acc2[j] = __builtin_amdgcn_mfma_f32_16x16x32_bf16(a2, b2, acc2[j], 0, 0, 0);
      }
    }
    float4 bq = *(const float4*)&bias_perm[hp * 128 + n * 8 + qq * 4];
#pragma unroll
    for (int r = 0; r < 4; ++r) {
      int row = dbase + 4 * q + r;
      if (row < N) {
        uint2 o;
        o.x = pack2(elu1(acc2[0][r] + bq.x), elu1(acc2[1][r] + bq.y));
        o.y = pack2(elu1(acc2[2][r] + bq.z), elu1(acc2[3][r] + bq.w));
        *(uint2*)&out1[(size_t)row * 512 + hp * 128 + n * 8 + qq * 4] = o;
      }
    }
  }
}

// ---------- layer 2: MFMA bf16 GEMM (k-dim permuted to match out1bf) ----------
__global__ __launch_bounds__(256) void gemm2_mfma_kernel(
    const unsigned short* __restrict__ x2bf,    // N x 512 bf16 (PERMUTED k)
    const unsigned short* __restrict__ W2frag,  // [16ks][4nt][64][8] bf16 (perm k)
    const float* __restrict__ att_src,          // 64
    const float* __restrict__ att_dst,
    unsigned short* __restrict__ h2,            // N x 64 bf16 (natural)
    float* __restrict__ a_s, float* __restrict__ a_d,  // N
    int N) {
  int t = threadIdx.x;
  int w = t >> 6, lane = t & 63;
  int quad = lane >> 4, l16 = lane & 15;
  int rowbase = blockIdx.x * 64 + w * 16;

  floatx4 acc[4] = {};
  int r0 = rowbase + l16; if (r0 >= N) r0 = N - 1;
  const unsigned short* p0 = x2bf + (size_t)r0 * 512 + quad * 8;
#pragma unroll
  for (int ks = 0; ks < 16; ++ks) {
    short8 a0 = *(const short8*)(p0 + ks * 32);
#pragma unroll
    for (int nt = 0; nt < 4; ++nt) {
      short8 b = *(const short8*)&W2frag[((ks * 4 + nt) * 64 + lane) * 8];
      acc[nt] = __builtin_amdgcn_mfma_f32_16x16x32_bf16(a0, b, acc[nt], 0, 0, 0);
    }
  }

  float asw[4], adw[4];
#pragma unroll
  for (int nt = 0; nt < 4; ++nt) {
    asw[nt] = att_src[nt * 16 + l16];
    adw[nt] = att_dst[nt * 16 + l16];
  }
  float ps[4] = {}, pd[4] = {};
#pragma unroll
  for (int nt = 0; nt < 4; ++nt)
#pragma unroll
    for (int r = 0; r < 4; ++r) {
      float v = acc[nt][r];
      int row = rowbase + quad * 4 + r;
      if (row < N) h2[(size_t)row * 64 + nt * 16 + l16] = f2bbits(v);
      ps[r] += v * asw[nt];
      pd[r] += v * adw[nt];
    }
#pragma unroll
  for (int r = 0; r < 4; ++r) {
    float p = ps[r], q = pd[r];
#pragma unroll
    for (int off = 1; off < 16; off <<= 1) {
      p += __shfl_xor(p, off);
      q += __shfl_xor(q, off);
    }
    int row = rowbase + quad * 4 + r;
    if (l16 == 0 && row < N) {
      a_s[row] = p;
      a_d[row] = q;
    }
  }
}

// H=1, quarter-wave edge grouping (h2 natural layout).
__global__ void gat_agg1_kernel(const int* __restrict__ rowptr,
                                const int* __restrict__ col,
                                const float* __restrict__ a_s,
                                const float* __restrict__ a_d,
                                const unsigned short* __restrict__ hfeat,
                                const float* __restrict__ bias,
                                unsigned short* __restrict__ out, int N) {
  int wave = threadIdx.x >> 6, lane = threadIdx.x & 63;
  int d = blockIdx.x * 4 + wave;
  if (d >= N) return;
  int beg = rowptr[d], end = rowptr[d + 1];
  int qg = lane >> 4, l16 = lane & 15;
  float adv = a_d[d];
  const uint2* hfu = (const uint2*)hfeat;
  float acc[4] = {};
  float wsum = 0.f;
#pragma unroll 2
  for (int i = beg + qg; i < end; i += 4) {
    int s = col[i] & SMASK;
    float v = a_s[s] + adv;
    v = v > 0.f ? v : NEG * v;
    float wv = __expf(v);
    wsum += wv;
    uint2 u = hfu[(size_t)s * 16 + l16];
    acc[0] += wv * blo(u.x); acc[1] += wv * bhi(u.x);
    acc[2] += wv * blo(u.y); acc[3] += wv * bhi(u.y);
  }
#pragma unroll
  for (int off = 16; off <= 32; off <<= 1) {
#pragma unroll
    for (int j = 0; j < 4; ++j) acc[j] += __shfl_xor(acc[j], off);
    wsum += __shfl_xor(wsum, off);
  }
  float winv = 1.f / (wsum + 1e-16f);
  float4 bb = ((const float4*)bias)[l16];
  float r0 = elu1(acc[0] * winv + bb.x), r1 = elu1(acc[1] * winv + bb.y);
  float r2 = elu1(acc[2] * winv + bb.z), r3 = elu1(acc[3] * winv + bb.w);
  if (qg == 0) {
    uint2 o; o.x = pack2(r0, r1); o.y = pack2(r2, r3);
    ((uint2*)out)[(size_t)d * 16 + l16] = o;
  }
}

// ---------- pooling: 16 nodes per wave ----------
__global__ void pool_kernel(const unsigned short* __restrict__ out2,
                            const int* __restrict__ batch,
                            float* __restrict__ pooled, int N) {
  int wave = threadIdx.x >> 6, lane = threadIdx.x & 63;
  int seg = blockIdx.x * 4 + wave;
  int start = seg * 16;
  if (start >= N) return;
  int end = min(start + 16, N);
  int cur = batch[start];
  float acc = 0.f;
  for (int n = start; n < end; ++n) {
    int bn = batch[n];
    if (bn != cur) {
      unsafeAtomicAdd(&pooled[cur * 64 + lane], acc);
      acc = 0.f; cur = bn;
    }
    acc += bu(out2[(size_t)n * 64 + lane]);
  }
  unsafeAtomicAdd(&pooled[cur * 64 + lane], acc);
}

// ---------- MLP head + log_softmax: one block (one wave) per graph ----------
__global__ void head_kernel(const float* __restrict__ pooled,
                            const float* __restrict__ lin1_w,
                            const float* __restrict__ lin1_b,
                            const float* __restrict__ lin2_w,
                            const float* __restrict__ lin2_b,
                            const void* __restrict__ x_raw,
                            void* __restrict__ outv) {
  __shared__ float P[C];
  __shared__ float Zs[C];
  __shared__ float Ls[K];
  __shared__ float lse_s;
  __shared__ int fl;
  int isbf = detect_dev(x_raw, &fl);
  int g = blockIdx.x, t = threadIdx.x;   // 64 threads
  P[t] = pooled[g * C + t];
  __syncthreads();
  float acc = lin1_b[t];
  for (int k = 0; k < C; ++k) acc += P[k] * lin1_w[k * C + t];
  Zs[t] = elu1(acc);
  __syncthreads();
  if (t < K) {
    float a = lin2_b[t];
    for (int k = 0; k < C; ++k) a += Zs[k] * lin2_w[k * K + t];
    Ls[t] = a;
  }
  __syncthreads();
  if (t == 0) {
    float mx = -1e30f;
    for (int c = 0; c < K; ++c) mx = fmaxf(mx, Ls[c]);
    float s = 0.f;
    for (int c = 0; c < K; ++c) s += __expf(Ls[c] - mx);
    lse_s = mx + __logf(s);
  }
  __syncthreads();
  if (t < K) {
    float val = Ls[t] - lse_s;
    if (isbf) ((__hip_bfloat16*)outv)[g * K + t] = __float2bfloat16(val);
    else      ((float*)outv)[g * K + t] = val;
  }
}

extern "C" void kernel_launch(void* const* d_in, const int* in_sizes, int n_in,
                              void* d_out, int out_size, void* d_ws, size_t ws_size,
                              hipStream_t stream) {
  const void* x_raw = d_in[0];
  const int*  ei    = (const int*)d_in[1];
  const int*  batch = (const int*)d_in[2];

  const int N    = in_sizes[2];
  const int E    = in_sizes[1] / 2;
  const int Etot = E + N;
  const int nb   = (N + 255) / 256;

  float* ws   = (float*)d_ws;
  size_t off  = 0;

  float* wts = ws + off; off += 6544;
  float* b1w  = wts + 1024;
  float* as2w = wts + 1536;
  float* ad2w = wts + 1600;
  float* b2w  = wts + 1664;
  float* l1w  = wts + 1728;
  float* l1b  = wts + 5824;
  float* l2w  = wts + 5888;
  float* l2b  = wts + 6528;

  unsigned short* xbf    = (unsigned short*)(ws + off); off += (size_t)N * 64;
  unsigned short* w1frag = (unsigned short*)(ws + off); off += 32768;
  unsigned short* w2frag = (unsigned short*)(ws + off); off += 16384;
  unsigned short* vfrag  = (unsigned short*)(ws + off); off += 1024;
  unsigned short* wedge  = (unsigned short*)(ws + off); off += (size_t)Etot * 4;
  unsigned short* out1bf = (unsigned short*)(ws + off); off += (size_t)N * 256;
  unsigned short* h2bf   = (unsigned short*)(ws + off); off += (size_t)N * 32;
  unsigned short* out2bf = (unsigned short*)(ws + off); off += (size_t)N * 32;
  float* as1  = ws + off; off += (size_t)N * H1;
  float* ad1  = ws + off; off += (size_t)N * H1;
  float* as2  = ws + off; off += (size_t)N;
  float* ad2  = ws + off; off += (size_t)N;
  float* pooled = ws + off; off += (size_t)B * C;

  int* ibase  = (int*)(ws + off);
  int* deg    = ibase;                 ibase += N;
  int* cursor = ibase;                 ibase += N;
  int* rowptr = ibase;                 ibase += N + 1;
  int* locals = ibase;                 ibase += N;
  int* bsum   = ibase;                 ibase += 256;
  int* col    = ibase;                 ibase += Etot;

  // ---- prep ----
  fused_prep_kernel<<<1024, 256, 0, stream>>>(
      x_raw, d_in[3], d_in[4], d_in[5], d_in[6], d_in[7], d_in[8], d_in[9],
      d_in[10], d_in[11], d_in[12], d_in[13], d_in[14],
      xbf, w1frag, w2frag, vfrag, wts, deg, pooled, in_sizes[0], N);

  // ---- CSR: deg + scans ----
  deg_count_kernel<<<(Etot + 255) / 256, 256, 0, stream>>>(ei, E, Etot, deg);
  scan_block_kernel<<<nb, 256, 0, stream>>>(deg, locals, bsum, N);
  scan_finish_kernel<<<nb, 256, 0, stream>>>(locals, bsum, nb, rowptr, cursor, N, Etot);

  // ---- layer-1 attention scalars via factored V (tiny MFMA GEMM) ----
  att_scalars_kernel<<<(N + 63) / 64, 256, 0, stream>>>(xbf, vfrag, as1, ad1, N);

  // ---- CSR fill + per-edge softmax weights (bf16) ----
  fill_weight_kernel<<<(Etot + 255) / 256, 256, 0, stream>>>(
      ei, E, Etot, as1, ad1, cursor, col, wedge);

  // ---- MFMA x-space aggregation + W1 GEMM -> out1 ----
  aggx_gemm1_kernel<<<(N + 15) / 16, 512, 0, stream>>>(
      xbf, w1frag, rowptr, col, wedge, b1w, out1bf, N);

  // ---- layer 2 ----
  gemm2_mfma_kernel<<<(N + 63) / 64, 256, 0, stream>>>(out1bf, w2frag, as2w, ad2w,
                                                       h2bf, as2, ad2, N);
  gat_agg1_kernel<<<(N + 3) / 4, 256, 0, stream>>>(rowptr, col, as2, ad2, h2bf, b2w, out2bf, N);

  // ---- pool + head ----
  pool_kernel<<<(N + 63) / 64, 256, 0, stream>>>(out2bf, batch, pooled, N);
  head_kernel<<<B, 64, 0, stream>>>(pooled, l1w, l1b, l2w, l2b, x_raw, (void*)d_out);
}